// Round 3
// baseline (838.164 us; speedup 1.0000x reference)
//
#include <hip/hip_runtime.h>
#include <hip/hip_bf16.h>
#include <math.h>

// Problem constants
#define TT 1024
#define DIM 1024
#define HH 8
#define QLR 768
#define KVLR 512
#define DNOPE 128
#define DROPE 64
#define DV 128
#define DK 192            // DNOPE + DROPE
#define HDK (HH*DK)       // 1536
#define HKV (HH*(DNOPE+DV)) // 2048

// ---------------------------------------------------------------------------
// Generic f32 GEMM: C = A(MxK) @ B(KxN), row-major, 64x64 tile, 4x4/thread.
// ---------------------------------------------------------------------------
__global__ __launch_bounds__(256) void gemm64(
    const float* __restrict__ A, const float* __restrict__ B,
    float* __restrict__ C, int M, int N, int K)
{
    __shared__ float As[16][64];   // [k][m]
    __shared__ float Bs[16][64];   // [k][n]
    const int tid = threadIdx.x;
    const int bm = blockIdx.y * 64, bn = blockIdx.x * 64;
    const int tm = tid >> 4, tn = tid & 15;
    const int ar = tid >> 2, ak = (tid & 3) * 4;
    const int bk = tid >> 4, bc = (tid & 15) * 4;

    float acc[4][4];
#pragma unroll
    for (int i = 0; i < 4; i++)
#pragma unroll
        for (int j = 0; j < 4; j++) acc[i][j] = 0.f;

    for (int k0 = 0; k0 < K; k0 += 16) {
        float4 av = *(const float4*)&A[(size_t)(bm + ar) * K + k0 + ak];
        float4 bv = *(const float4*)&B[(size_t)(k0 + bk) * N + bn + bc];
        __syncthreads();
        As[ak + 0][ar] = av.x; As[ak + 1][ar] = av.y;
        As[ak + 2][ar] = av.z; As[ak + 3][ar] = av.w;
        *(float4*)&Bs[bk][bc] = bv;
        __syncthreads();
#pragma unroll
        for (int kk = 0; kk < 16; kk++) {
            float4 a4 = *(const float4*)&As[kk][tm * 4];
            float4 b4 = *(const float4*)&Bs[kk][tn * 4];
            float aa[4] = {a4.x, a4.y, a4.z, a4.w};
            float bb[4] = {b4.x, b4.y, b4.z, b4.w};
#pragma unroll
            for (int i = 0; i < 4; i++)
#pragma unroll
                for (int j = 0; j < 4; j++) acc[i][j] += aa[i] * bb[j];
        }
    }
#pragma unroll
    for (int i = 0; i < 4; i++) {
        float4 v = make_float4(acc[i][0], acc[i][1], acc[i][2], acc[i][3]);
        *(float4*)&C[(size_t)(bm + tm * 4 + i) * N + bn + tn * 4] = v;
    }
}

// ---------------------------------------------------------------------------
__global__ __launch_bounds__(256) void rmsnorm_rows(
    const float* __restrict__ in, int in_stride, const float* __restrict__ w,
    float* __restrict__ out, int out_stride, int ncols, float inv_n)
{
    const int t = blockIdx.x;
    const int tid = threadIdx.x;
    const float* row = in + (size_t)t * in_stride;
    float ss = 0.f;
    for (int c = tid; c < ncols; c += 256) { float v = row[c]; ss += v * v; }
#pragma unroll
    for (int m = 1; m < 64; m <<= 1) ss += __shfl_xor(ss, m);
    __shared__ float red[4];
    if ((tid & 63) == 0) red[tid >> 6] = ss;
    __syncthreads();
    float tot = red[0] + red[1] + red[2] + red[3];
    float scale = rsqrtf(tot * inv_n + 1e-5f);
    for (int c = tid; c < ncols; c += 256)
        out[(size_t)t * out_stride + c] = row[c] * scale * w[c];
}

// ---------------------------------------------------------------------------
__global__ __launch_bounds__(256) void sigmoid_bias(
    float* __restrict__ g, const float* __restrict__ b, int ncols, int total)
{
    int i = blockIdx.x * 256 + threadIdx.x;
    if (i < total) {
        float z = g[i] + b[i % ncols];
        g[i] = 1.f / (1.f + expf(-z));
    }
}

// ---------------------------------------------------------------------------
__global__ __launch_bounds__(256) void beta_kernel(
    const float* __restrict__ x, const float* __restrict__ wb,
    float* __restrict__ beta)
{
    const int lane = threadIdx.x & 63, wv = threadIdx.x >> 6;
    const int p = blockIdx.x * 4 + wv;        // p = t*8 + h
    const int t = p >> 3, h = p & 7;
    const float* xr = x + (size_t)t * DIM;
    float s = 0.f;
    for (int e = lane; e < DIM; e += 64) s += xr[e] * wb[e * HH + h];
#pragma unroll
    for (int m = 1; m < 64; m <<= 1) s += __shfl_xor(s, m);
    if (lane == 0) beta[p] = 1.f / (1.f + expf(-s));
}

// ---------------------------------------------------------------------------
__global__ __launch_bounds__(256) void prep_qk(
    float* __restrict__ q, const float* __restrict__ kvb,
    const float* __restrict__ kv_all, float* __restrict__ kn)
{
    const int lane = threadIdx.x & 63, wv = threadIdx.x >> 6;
    const int p = blockIdx.x * 4 + wv;
    const int t = p >> 3, h = p & 7;

    float* qrow = q + (size_t)t * HDK + h * DK;
    float q0 = qrow[lane], q1 = qrow[lane + 64], q2 = qrow[lane + 128];
    float ss = q0 * q0 + q1 * q1 + q2 * q2;
#pragma unroll
    for (int m = 1; m < 64; m <<= 1) ss += __shfl_xor(ss, m);
    float sc = rsqrtf(ss + 1e-6f) * 0.07216878364870323f;  // * DK^-0.5
    qrow[lane] = q0 * sc; qrow[lane + 64] = q1 * sc; qrow[lane + 128] = q2 * sc;

    const float* knope = kvb + (size_t)t * HKV + h * (DNOPE + DV);
    float k0 = knope[lane], k1 = knope[lane + 64];
    float k2 = kv_all[(size_t)t * (KVLR + DROPE) + KVLR + lane];
    float ks = k0 * k0 + k1 * k1 + k2 * k2;
#pragma unroll
    for (int m = 1; m < 64; m <<= 1) ks += __shfl_xor(ks, m);
    float kc = rsqrtf(ks + 1e-6f);
    float* kout = kn + (size_t)t * HDK + h * DK;
    kout[lane] = k0 * kc; kout[lane + 64] = k1 * kc; kout[lane + 128] = k2 * kc;
}

// ---------------------------------------------------------------------------
// Pre-pass for the scan's input-only scalars/vectors (all premultiplied by
// beta_t):
//   kaab[t,h,d] = b_t * k_t[d] * a_t[d] * a_{t-1}[d]
//   bD2[t,h]    = b_t * sum_d k_t a_t k_{t-1}
//   bR2[t,h]    = b_t * sum_d k_t a_t a_{t-1} k_{t-2}
// One wave per (t,h); 3 dims/lane.
// ---------------------------------------------------------------------------
__global__ __launch_bounds__(256) void prep_scalars(
    const float* __restrict__ kn, const float* __restrict__ ag,
    const float* __restrict__ beta, float* __restrict__ kaab,
    float* __restrict__ bD2, float* __restrict__ bR2)
{
    const int lane = threadIdx.x & 63, wv = threadIdx.x >> 6;
    const int p = blockIdx.x * 4 + wv;        // p = t*8 + h
    const int t = p >> 3, h = p & 7;
    const size_t rb = (size_t)t * HDK + h * DK;
    const float b = beta[p];

    float pd = 0.f, pr = 0.f;
#pragma unroll
    for (int j = 0; j < 3; j++) {
        const int d = lane + j * 64;
        float k0 = kn[rb + d], a0 = ag[rb + d];
        float k1 = (t >= 1) ? kn[rb - HDK + d] : 0.f;
        float a1 = (t >= 1) ? ag[rb - HDK + d] : 1.f;
        float k2 = (t >= 2) ? kn[rb - 2 * (size_t)HDK + d] : 0.f;
        float ka = k0 * a0;
        float kaa = ka * a1;
        kaab[rb + d] = b * kaa;
        pd += ka * k1;
        pr += kaa * k2;
    }
#pragma unroll
    for (int m = 1; m < 64; m <<= 1) { pd += __shfl_xor(pd, m); pr += __shfl_xor(pr, m); }
    if (lane == 0) { bD2[p] = b * pd; bR2[p] = b * pr; }
}

// ---------------------------------------------------------------------------
// 16-lane sum reduction, pure DPP (no LDS pipe): xor1, xor2, then
// row_half_mirror (== xor4 once quads are uniform), row_mirror (== xor8).
// ---------------------------------------------------------------------------
__device__ __forceinline__ float red16(float x) {
    x += __int_as_float(__builtin_amdgcn_update_dpp(0, __float_as_int(x), 0xB1, 0xF, 0xF, false));
    x += __int_as_float(__builtin_amdgcn_update_dpp(0, __float_as_int(x), 0x4E, 0xF, 0xF, false));
    x += __int_as_float(__builtin_amdgcn_update_dpp(0, __float_as_int(x), 0x141, 0xF, 0xF, false));
    x += __int_as_float(__builtin_amdgcn_update_dpp(0, __float_as_int(x), 0x140, 0xF, 0xF, false));
    return x;
}

__device__ __forceinline__ void load12(float* dst, const float* p) {
    float4 f0 = *(const float4*)(p);
    float4 f1 = *(const float4*)(p + 4);
    float4 f2 = *(const float4*)(p + 8);
    dst[0]=f0.x; dst[1]=f0.y; dst[2]=f0.z; dst[3]=f0.w;
    dst[4]=f1.x; dst[5]=f1.y; dst[6]=f1.z; dst[7]=f1.w;
    dst[8]=f2.x; dst[9]=f2.y; dst[10]=f2.z; dst[11]=f2.w;
}

// ---------------------------------------------------------------------------
// KDA scan v3. 16 lanes per (h,v)-column, 12 dims/lane, pure-DPP reductions.
// Scalar recurrence (per column):
//   u_t = b_t v_t - R1'_t - u_{t-2} bR2_t - u_{t-1} bD2_t
//   R1'_t = red16( kaab_t . sd_{t-2} )      (2 steps of slack)
//   sd advance (lagged): sd_{t-1} = a_{t-1} o (sd_{t-2} + u_{t-2} k_{t-2})
//   o_{t-1} = red16( q_{t-1} o (sd_{t-1} + u_{t-1} k_{t-1}) )
// Depth-4 rotating register buffers; loads prefetched ~2 steps ahead.
// grid: 64 blocks x 256 (16 columns/block).
// ---------------------------------------------------------------------------
__global__ __launch_bounds__(256) void kda_scan3(
    const float* __restrict__ qn, const float* __restrict__ kn,
    const float* __restrict__ ag, const float* __restrict__ kaab,
    const float* __restrict__ kvb, const float* __restrict__ beta,
    const float* __restrict__ bD2, const float* __restrict__ bR2,
    float* __restrict__ o)
{
    const int tid = threadIdx.x;
    const int lane = tid & 63, wv = tid >> 6;
    const int grp = lane >> 4, l = lane & 15;
    const int col = blockIdx.x * 16 + wv * 4 + grp;   // 0..1023
    const int h = col >> 7, c = col & 127;

    const size_t eb = (size_t)h * DK + l * 12;
    const float* kp = kn + eb;
    const float* ap = ag + eb;
    const float* qp = qn + eb;
    const float* cp = kaab + eb;
    const float* vp = kvb + (size_t)h * (DNOPE + DV) + DNOPE + c;
    const float* bp = beta + h;
    const float* d2p = bD2 + h;
    const float* r2p = bR2 + h;
    float* op = o + (size_t)h * DV + c;

    float sd[12];
    float kb[4][12], ab_[4][12], qb[4][12], cb[4][12];
    float vb[4], bb[4], d2b[4], r2b[4];

#pragma unroll
    for (int j = 0; j < 12; j++) sd[j] = 0.f;
#pragma unroll
    for (int z = 0; z < 4; z++) {
#pragma unroll
        for (int j = 0; j < 12; j++) { kb[z][j]=0.f; ab_[z][j]=0.f; qb[z][j]=0.f; cb[z][j]=0.f; }
        vb[z]=0.f; bb[z]=0.f; d2b[z]=0.f; r2b[z]=0.f;
    }

    // Preload t=0 (k,a,q,kaa,scalars) and t=1 (a,q,kaa,scalars).
    load12(kb[0], kp);
    load12(ab_[0], ap); load12(ab_[1], ap + HDK);
    load12(qb[0], qp);  load12(qb[1], qp + HDK);
    load12(cb[0], cp);  load12(cb[1], cp + HDK);
    vb[0] = vp[0]; vb[1] = vp[HKV];
    bb[0] = bp[0]; bb[1] = bp[HH];
    d2b[0] = d2p[0]; d2b[1] = d2p[HH];
    r2b[0] = r2p[0]; r2b[1] = r2p[HH];

    float u1 = 0.f, u2 = 0.f;

    for (int tb = 0; tb < TT; tb += 4) {
#pragma unroll
        for (int ti = 0; ti < 4; ti++) {
            const int t = tb + ti;
            const int s   = t & 3;
            const int sm1 = (t + 3) & 3;      // t-1
            const int sm2 = (t + 2) & 3;      // t-2 (== (t+2)&3)
            const int sp1 = (t + 1) & 3;      // t+1 (k load target)
            const int sp2 = (t + 2) & 3;      // t+2 (a/q/kaa/scalar load target)

            // ---- prefetch ----
            int tf2 = t + 2; if (tf2 > TT - 1) tf2 = TT - 1;
            int tf1 = t + 1; if (tf1 > TT - 1) tf1 = TT - 1;
            {
                const size_t ro2 = (size_t)tf2 * HDK;
                const size_t ro1 = (size_t)tf1 * HDK;
                load12(ab_[sp2], ap + ro2);
                load12(qb[sp2],  qp + ro2);
                load12(cb[sp2],  cp + ro2);
                load12(kb[sp1],  kp + ro1);
                vb[sp2]  = vp[(size_t)tf2 * HKV];
                bb[sp2]  = bp[(size_t)tf2 * HH];
                d2b[sp2] = d2p[(size_t)tf2 * HH];
                r2b[sp2] = r2p[(size_t)tf2 * HH];
            }

            // ---- R1' = red16(kaab_t . sd_{t-2}) ----
            float p0 = 0.f, p1 = 0.f, p2 = 0.f, p3 = 0.f;
#pragma unroll
            for (int j = 0; j < 12; j += 4) {
                p0 += cb[s][j]     * sd[j];
                p1 += cb[s][j + 1] * sd[j + 1];
                p2 += cb[s][j + 2] * sd[j + 2];
                p3 += cb[s][j + 3] * sd[j + 3];
            }
            float r1 = red16((p0 + p1) + (p2 + p3));

            // ---- u_t (critical scalar chain: one fma from u1) ----
            float base = bb[s] * vb[s] - u2 * r2b[s] - r1;
            float ut = base - u1 * d2b[s];

            // ---- advance sd -> sd_{t-1} ----
#pragma unroll
            for (int j = 0; j < 12; j++)
                sd[j] = ab_[sm1][j] * fmaf(u2, kb[sm2][j], sd[j]);

            // ---- output o_{t-1} = red16(q_{t-1} o (sd_{t-1} + u_{t-1} k_{t-1})) ----
            float o0 = 0.f, o1 = 0.f, o2 = 0.f, o3 = 0.f;
#pragma unroll
            for (int j = 0; j < 12; j += 4) {
                o0 += qb[sm1][j]     * fmaf(u1, kb[sm1][j],     sd[j]);
                o1 += qb[sm1][j + 1] * fmaf(u1, kb[sm1][j + 1], sd[j + 1]);
                o2 += qb[sm1][j + 2] * fmaf(u1, kb[sm1][j + 2], sd[j + 2]);
                o3 += qb[sm1][j + 3] * fmaf(u1, kb[sm1][j + 3], sd[j + 3]);
            }
            float ov = red16((o0 + o1) + (o2 + o3));
            if (isnan(ov)) ov = 0.f;
            else if (isinf(ov)) ov = ov > 0.f ? 1e4f : -1e4f;
            if (l == 0 && t > 0) op[(size_t)(t - 1) * (HH * DV)] = ov;

            u2 = u1; u1 = ut;
        }
    }

    // Epilogue: o_{TT-1}. Slots: (TT-1)&3 == 3, (TT-2)&3 == 2 (both intact).
    {
#pragma unroll
        for (int j = 0; j < 12; j++)
            sd[j] = ab_[3][j] * fmaf(u2, kb[2][j], sd[j]);
        float o0 = 0.f, o1 = 0.f, o2 = 0.f, o3 = 0.f;
#pragma unroll
        for (int j = 0; j < 12; j += 4) {
            o0 += qb[3][j]     * fmaf(u1, kb[3][j],     sd[j]);
            o1 += qb[3][j + 1] * fmaf(u1, kb[3][j + 1], sd[j + 1]);
            o2 += qb[3][j + 2] * fmaf(u1, kb[3][j + 2], sd[j + 2]);
            o3 += qb[3][j + 3] * fmaf(u1, kb[3][j + 3], sd[j + 3]);
        }
        float ov = red16((o0 + o1) + (o2 + o3));
        if (isnan(ov)) ov = 0.f;
        else if (isinf(ov)) ov = ov > 0.f ? 1e4f : -1e4f;
        if (l == 0) op[(size_t)(TT - 1) * (HH * DV)] = ov;
    }
}

// ---------------------------------------------------------------------------
extern "C" void kernel_launch(void* const* d_in, const int* in_sizes, int n_in,
                              void* d_out, int out_size, void* d_ws, size_t ws_size,
                              hipStream_t stream)
{
    const float* x         = (const float*)d_in[0];
    // d_in[1] = cos, d_in[2] = sin : unused by the reference
    const float* wq_a      = (const float*)d_in[3];
    const float* q_norm_w  = (const float*)d_in[4];
    const float* wq_b      = (const float*)d_in[5];
    const float* wkv_a     = (const float*)d_in[6];
    const float* kv_norm_w = (const float*)d_in[7];
    const float* wkv_b     = (const float*)d_in[8];
    const float* wg_w      = (const float*)d_in[9];
    const float* wg_b      = (const float*)d_in[10];
    const float* wb        = (const float*)d_in[11];
    const float* wo        = (const float*)d_in[12];
    float* out = (float*)d_out;

    float* ws = (float*)d_ws;
    float* xq     = ws;                    // T x 768
    float* xqn    = xq     + TT * QLR;     // T x 768
    float* kv_all = xqn    + TT * QLR;     // T x 576
    float* kvn    = kv_all + TT * (KVLR + DROPE); // T x 512
    float* ag     = kvn    + TT * KVLR;    // T x 1536 (decay, in-place sigmoid)
    float* betab  = ag     + TT * HDK;     // T x 8
    float* qn     = betab  + TT * HH;      // T x 1536 (in-place l2norm)
    float* kvb    = qn     + TT * HDK;     // T x 2048
    float* kn     = kvb    + TT * HKV;     // T x 1536
    float* ob     = kn     + TT * HDK;     // T x 1024
    float* kaab   = ob     + TT * DIM;     // T x 1536
    float* bD2    = kaab   + TT * HDK;     // T x 8
    float* bR2    = bD2    + TT * HH;      // T x 8

    dim3 blk(256);

    // x projections
    gemm64<<<dim3(QLR / 64, TT / 64), blk, 0, stream>>>(x, wq_a, xq, TT, QLR, DIM);
    gemm64<<<dim3((KVLR + DROPE) / 64, TT / 64), blk, 0, stream>>>(x, wkv_a, kv_all, TT, KVLR + DROPE, DIM);
    gemm64<<<dim3(HDK / 64, TT / 64), blk, 0, stream>>>(x, wg_w, ag, TT, HDK, DIM);

    // norms
    rmsnorm_rows<<<TT, blk, 0, stream>>>(xq, QLR, q_norm_w, xqn, QLR, QLR, 1.f / QLR);
    rmsnorm_rows<<<TT, blk, 0, stream>>>(kv_all, KVLR + DROPE, kv_norm_w, kvn, KVLR, KVLR, 1.f / KVLR);

    // low-rank expansions
    gemm64<<<dim3(HDK / 64, TT / 64), blk, 0, stream>>>(xqn, wq_b, qn, TT, HDK, QLR);
    gemm64<<<dim3(HKV / 64, TT / 64), blk, 0, stream>>>(kvn, wkv_b, kvb, TT, HKV, KVLR);

    // gates
    sigmoid_bias<<<(TT * HDK + 255) / 256, blk, 0, stream>>>(ag, wg_b, HDK, TT * HDK);
    beta_kernel<<<TT * HH / 4, blk, 0, stream>>>(x, wb, betab);

    // l2norm q, build+l2norm k
    prep_qk<<<TT * HH / 4, blk, 0, stream>>>(qn, kvb, kv_all, kn);

    // input-only scalar/vector precompute for the scan
    prep_scalars<<<TT * HH / 4, blk, 0, stream>>>(kn, ag, betab, kaab, bD2, bR2);

    // pipelined gated delta-rule scan (pure-DPP reductions)
    kda_scan3<<<64, blk, 0, stream>>>(qn, kn, ag, kaab, kvb, betab, bD2, bR2, ob);

    // output projection
    gemm64<<<dim3(DIM / 64, TT / 64), blk, 0, stream>>>(ob, wo, out, TT, DIM, DIM);
}

// Round 4
// 766.230 us; speedup vs baseline: 1.0939x; 1.0939x over previous
//
#include <hip/hip_runtime.h>
#include <hip/hip_bf16.h>
#include <math.h>

// Problem constants
#define TT 1024
#define DIM 1024
#define HH 8
#define QLR 768
#define KVLR 512
#define DNOPE 128
#define DROPE 64
#define DV 128
#define DK 192            // DNOPE + DROPE
#define HDK (HH*DK)       // 1536
#define HKV (HH*(DNOPE+DV)) // 2048
#define TB 16             // scan tile (timesteps per LDS buffer)

// ---------------------------------------------------------------------------
// Generic f32 GEMM: C = A(MxK) @ B(KxN), row-major, 64x64 tile, 4x4/thread.
// ---------------------------------------------------------------------------
__global__ __launch_bounds__(256) void gemm64(
    const float* __restrict__ A, const float* __restrict__ B,
    float* __restrict__ C, int M, int N, int K)
{
    __shared__ float As[16][64];   // [k][m]
    __shared__ float Bs[16][64];   // [k][n]
    const int tid = threadIdx.x;
    const int bm = blockIdx.y * 64, bn = blockIdx.x * 64;
    const int tm = tid >> 4, tn = tid & 15;
    const int ar = tid >> 2, ak = (tid & 3) * 4;
    const int bk = tid >> 4, bc = (tid & 15) * 4;

    float acc[4][4];
#pragma unroll
    for (int i = 0; i < 4; i++)
#pragma unroll
        for (int j = 0; j < 4; j++) acc[i][j] = 0.f;

    for (int k0 = 0; k0 < K; k0 += 16) {
        float4 av = *(const float4*)&A[(size_t)(bm + ar) * K + k0 + ak];
        float4 bv = *(const float4*)&B[(size_t)(k0 + bk) * N + bn + bc];
        __syncthreads();
        As[ak + 0][ar] = av.x; As[ak + 1][ar] = av.y;
        As[ak + 2][ar] = av.z; As[ak + 3][ar] = av.w;
        *(float4*)&Bs[bk][bc] = bv;
        __syncthreads();
#pragma unroll
        for (int kk = 0; kk < 16; kk++) {
            float4 a4 = *(const float4*)&As[kk][tm * 4];
            float4 b4 = *(const float4*)&Bs[kk][tn * 4];
            float aa[4] = {a4.x, a4.y, a4.z, a4.w};
            float bb[4] = {b4.x, b4.y, b4.z, b4.w};
#pragma unroll
            for (int i = 0; i < 4; i++)
#pragma unroll
                for (int j = 0; j < 4; j++) acc[i][j] += aa[i] * bb[j];
        }
    }
#pragma unroll
    for (int i = 0; i < 4; i++) {
        float4 v = make_float4(acc[i][0], acc[i][1], acc[i][2], acc[i][3]);
        *(float4*)&C[(size_t)(bm + tm * 4 + i) * N + bn + tn * 4] = v;
    }
}

// ---------------------------------------------------------------------------
// RMSNorm rows (in-place safe: barrier between read and write phases)
// ---------------------------------------------------------------------------
__global__ __launch_bounds__(256) void rmsnorm_rows(
    const float* __restrict__ in, int in_stride, const float* __restrict__ w,
    float* __restrict__ out, int out_stride, int ncols, float inv_n)
{
    const int t = blockIdx.x;
    const int tid = threadIdx.x;
    const float* row = in + (size_t)t * in_stride;
    float ss = 0.f;
    for (int c = tid; c < ncols; c += 256) { float v = row[c]; ss += v * v; }
#pragma unroll
    for (int m = 1; m < 64; m <<= 1) ss += __shfl_xor(ss, m);
    __shared__ float red[4];
    if ((tid & 63) == 0) red[tid >> 6] = ss;
    __syncthreads();
    float tot = red[0] + red[1] + red[2] + red[3];
    float scale = rsqrtf(tot * inv_n + 1e-5f);
    for (int c = tid; c < ncols; c += 256)
        out[(size_t)t * out_stride + c] = row[c] * scale * w[c];
}

// ---------------------------------------------------------------------------
// decay = sigmoid(gpre + bias[col]) written HEAD-MAJOR: a_h[h][t][192]
// ---------------------------------------------------------------------------
__global__ __launch_bounds__(256) void sigmoid_relayout(
    const float* __restrict__ g, const float* __restrict__ bias,
    float* __restrict__ a_h)
{
    int i = blockIdx.x * 256 + threadIdx.x;   // < TT*HDK
    int t = i / HDK, col = i - t * HDK;
    int h = col / DK, d = col - h * DK;
    float z = g[i] + bias[col];
    a_h[((size_t)h * TT + t) * DK + d] = 1.f / (1.f + expf(-z));
}

// ---------------------------------------------------------------------------
// beta[t,h] = sigmoid(x . wb[:,h]); stores both [t][8] and head-major [h][t]
// ---------------------------------------------------------------------------
__global__ __launch_bounds__(256) void beta_kernel(
    const float* __restrict__ x, const float* __restrict__ wb,
    float* __restrict__ beta, float* __restrict__ beta_h)
{
    const int lane = threadIdx.x & 63, wv = threadIdx.x >> 6;
    const int p = blockIdx.x * 4 + wv;        // p = t*8 + h
    const int t = p >> 3, h = p & 7;
    const float* xr = x + (size_t)t * DIM;
    float s = 0.f;
    for (int e = lane; e < DIM; e += 64) s += xr[e] * wb[e * HH + h];
#pragma unroll
    for (int m = 1; m < 64; m <<= 1) s += __shfl_xor(s, m);
    if (lane == 0) {
        float r = 1.f / (1.f + expf(-s));
        beta[p] = r;
        beta_h[(size_t)h * TT + t] = r;
    }
}

// ---------------------------------------------------------------------------
// l2norm(q)*DK^-0.5 and build+l2norm k; outputs HEAD-MAJOR [h][t][192].
// ---------------------------------------------------------------------------
__global__ __launch_bounds__(256) void prep_qk(
    const float* __restrict__ qraw, const float* __restrict__ kvb,
    const float* __restrict__ kv_all, float* __restrict__ q_h,
    float* __restrict__ k_h)
{
    const int lane = threadIdx.x & 63, wv = threadIdx.x >> 6;
    const int p = blockIdx.x * 4 + wv;
    const int t = p >> 3, h = p & 7;

    const float* qrow = qraw + (size_t)t * HDK + h * DK;
    float q0 = qrow[lane], q1 = qrow[lane + 64], q2 = qrow[lane + 128];
    float ss = q0 * q0 + q1 * q1 + q2 * q2;
#pragma unroll
    for (int m = 1; m < 64; m <<= 1) ss += __shfl_xor(ss, m);
    float sc = rsqrtf(ss + 1e-6f) * 0.07216878364870323f;  // * DK^-0.5
    float* qo = q_h + ((size_t)h * TT + t) * DK;
    qo[lane] = q0 * sc; qo[lane + 64] = q1 * sc; qo[lane + 128] = q2 * sc;

    const float* knope = kvb + (size_t)t * HKV + h * (DNOPE + DV);
    float k0 = knope[lane], k1 = knope[lane + 64];
    float k2 = kv_all[(size_t)t * (KVLR + DROPE) + KVLR + lane];
    float ks = k0 * k0 + k1 * k1 + k2 * k2;
#pragma unroll
    for (int m = 1; m < 64; m <<= 1) ks += __shfl_xor(ks, m);
    float kc = rsqrtf(ks + 1e-6f);
    float* ko = k_h + ((size_t)h * TT + t) * DK;
    ko[lane] = k0 * kc; ko[lane + 64] = k1 * kc; ko[lane + 128] = k2 * kc;
}

// ---------------------------------------------------------------------------
// Transpose v: kvb[t][h*256+128+c] -> v_h[h][c][t]
// ---------------------------------------------------------------------------
__global__ __launch_bounds__(256) void vtrans(
    const float* __restrict__ kvb, float* __restrict__ v_h)
{
    __shared__ float ld[128][129];
    const int h = blockIdx.x >> 3, tb = (blockIdx.x & 7) * 128;
    const int tid = threadIdx.x;
    for (int it = 0; it < 64; it++) {
        int tl = it * 2 + (tid >> 7);
        int c  = tid & 127;
        ld[tl][c] = kvb[(size_t)(tb + tl) * HKV + h * (DNOPE + DV) + DNOPE + c];
    }
    __syncthreads();
    for (int it = 0; it < 64; it++) {
        int c  = it * 2 + (tid >> 7);
        int tl = tid & 127;
        v_h[((size_t)h * DV + c) * TT + tb + tl] = ld[tl][c];
    }
}

// ---------------------------------------------------------------------------
// Input-only scalars (premultiplied by beta_t), head-major [h][t]:
//   d2_h = b_t sum_d k_t a_t k_{t-1};  r2_h = b_t sum_d k_t a_t a_{t-1} k_{t-2}
// ---------------------------------------------------------------------------
__global__ __launch_bounds__(256) void prep_scalars(
    const float* __restrict__ k_h, const float* __restrict__ a_h,
    const float* __restrict__ beta, float* __restrict__ d2_h,
    float* __restrict__ r2_h)
{
    const int lane = threadIdx.x & 63, wv = threadIdx.x >> 6;
    const int p = blockIdx.x * 4 + wv;        // p = t*8 + h
    const int t = p >> 3, h = p & 7;
    const size_t rb = ((size_t)h * TT + t) * DK;
    const float b = beta[p];

    float pd = 0.f, pr = 0.f;
#pragma unroll
    for (int j = 0; j < 3; j++) {
        const int d = lane + j * 64;
        float k0 = k_h[rb + d], a0 = a_h[rb + d];
        float k1 = (t >= 1) ? k_h[rb - DK + d] : 0.f;
        float a1 = (t >= 1) ? a_h[rb - DK + d] : 1.f;
        float k2 = (t >= 2) ? k_h[rb - 2 * DK + d] : 0.f;
        float ka = k0 * a0;
        pd += ka * k1;
        pr += ka * a1 * k2;
    }
#pragma unroll
    for (int m = 1; m < 64; m <<= 1) { pd += __shfl_xor(pd, m); pr += __shfl_xor(pr, m); }
    if (lane == 0) {
        d2_h[(size_t)h * TT + t] = b * pd;
        r2_h[(size_t)h * TT + t] = b * pr;
    }
}

// ---------------------------------------------------------------------------
// 32-lane sum reduction: 4 DPP stages + 1 ds_swizzle xor16 (validated R2).
// ---------------------------------------------------------------------------
__device__ __forceinline__ float red32(float x) {
    x += __int_as_float(__builtin_amdgcn_update_dpp(0, __float_as_int(x), 0xB1, 0xF, 0xF, false));
    x += __int_as_float(__builtin_amdgcn_update_dpp(0, __float_as_int(x), 0x4E, 0xF, 0xF, false));
    x += __int_as_float(__builtin_amdgcn_update_dpp(0, __float_as_int(x), 0x141, 0xF, 0xF, false));
    x += __int_as_float(__builtin_amdgcn_update_dpp(0, __float_as_int(x), 0x140, 0xF, 0xF, false));
    x += __int_as_float(__builtin_amdgcn_ds_swizzle(__float_as_int(x), 0x401F));
    return x;
}

// async global->LDS (width 16 / 4). LDS dest = uniform base + lane*size.
__device__ __forceinline__ void gl_lds16(const float* g, float* l) {
    __builtin_amdgcn_global_load_lds(
        (const __attribute__((address_space(1))) void*)g,
        (__attribute__((address_space(3))) void*)l, 16, 0, 0);
}
__device__ __forceinline__ void gl_lds4(const float* g, float* l) {
    __builtin_amdgcn_global_load_lds(
        (const __attribute__((address_space(1))) void*)g,
        (__attribute__((address_space(3))) void*)l, 4, 0, 0);
}

// ---------------------------------------------------------------------------
// KDA scan v4: LDS double-buffered tiles (TB=16 steps), 32 lanes/column,
// 6 dims/lane, scan3 algebra (verified):
//   entering step t: sd = S~_{t-2};  r1 = red32(sum k_t a_t a_{t-1} sd)
//   u_t = b(v_t - r1) - u_{t-2} r2_t - u_{t-1} d2_t    (r2/d2 pre-scaled by b)
//   sd <- a_{t-1} o (sd + u_{t-2} k_{t-2})   ( = S~_{t-1} )
//   o_{t-1} = red32(sum q_{t-1} o (sd + u_{t-1} k_{t-1}))
// grid: 128 blocks x 256 thr = 8 heads x 16 colgroups x 8 cols (32 lanes ea).
// ---------------------------------------------------------------------------
__global__ __launch_bounds__(256) void kda_scan4(
    const float* __restrict__ q_h, const float* __restrict__ k_h,
    const float* __restrict__ a_h, const float* __restrict__ v_h,
    const float* __restrict__ beta_h, const float* __restrict__ d2_h,
    const float* __restrict__ r2_h, float* __restrict__ o)
{
    __shared__ __align__(16) float Kt[2][TB][192];
    __shared__ __align__(16) float At[2][TB][192];
    __shared__ __align__(16) float Qt[2][TB][192];
    __shared__ __align__(16) float Vt[2][8][TB];
    __shared__ __align__(16) float St[2][3][TB];   // b, d2, r2

    const int tid = threadIdx.x;
    const int w = tid >> 6, lane = tid & 63;
    const int sub = lane >> 5, l = lane & 31;
    const int h = blockIdx.x >> 4, cg = blockIdx.x & 15;
    const int cb = w * 2 + sub;                  // column within block 0..7
    const int d4 = l * 4, dlo = 128 + l * 2;     // this lane's dims

    const float* kg = k_h + (size_t)h * TT * DK;
    const float* ag = a_h + (size_t)h * TT * DK;
    const float* qg = q_h + (size_t)h * TT * DK;
    const float* vg = v_h + ((size_t)h * DV + cg * 8) * TT;
    const float* bg = beta_h + (size_t)h * TT;
    const float* dg = d2_h + (size_t)h * TT;
    const float* rg = r2_h + (size_t)h * TT;
    float* op = o + (size_t)h * DV + cg * 8 + cb;

    auto stage = [&](int buf, int n) {
        const size_t toff = (size_t)n * TB * DK;
        if (w == 0) {
            const float* g = kg + toff; float* lb = &Kt[buf][0][0];
#pragma unroll
            for (int i = 0; i < 12; i++) gl_lds16(g + i * 256 + lane * 4, lb + i * 256);
        } else if (w == 1) {
            const float* g = ag + toff; float* lb = &At[buf][0][0];
#pragma unroll
            for (int i = 0; i < 12; i++) gl_lds16(g + i * 256 + lane * 4, lb + i * 256);
        } else if (w == 2) {
            const float* g = qg + toff; float* lb = &Qt[buf][0][0];
#pragma unroll
            for (int i = 0; i < 12; i++) gl_lds16(g + i * 256 + lane * 4, lb + i * 256);
        } else {
            if (lane < 32) {   // V: 8 cols x 16 t = 512 B; lane -> base + lane*16
                const float* g = vg + (size_t)(lane >> 2) * TT + n * TB + (lane & 3) * 4;
                gl_lds16(g, &Vt[buf][0][0]);
            }
            if (lane < 48) {   // St: 3 x 16 floats; lane -> base + lane*4
                const int which = lane >> 4, tt = lane & 15;
                const float* g = (which == 0 ? bg : which == 1 ? dg : rg) + n * TB + tt;
                gl_lds4(g, &St[buf][0][0]);
            }
        }
    };

    float sd[6], kp1[6], kp2[6], qpv[6], apv[6];
#pragma unroll
    for (int j = 0; j < 6; j++) { sd[j] = 0.f; kp1[j] = 0.f; kp2[j] = 0.f; qpv[j] = 0.f; apv[j] = 1.f; }
    float u1 = 0.f, u2 = 0.f;

    stage(0, 0);
    stage(1, 1);

    for (int n = 0; n < TT / TB; n++) {
        const int buf = n & 1;
        __syncthreads();   // own-wave vmcnt drained -> buf's tile is resident
#pragma unroll 4
        for (int tt = 0; tt < TB; tt++) {
            const int t = n * TB + tt;
            const float* Kr = &Kt[buf][tt][0];
            const float* Ar = &At[buf][tt][0];
            const float* Qr = &Qt[buf][tt][0];
            float kc[6], ac[6], qc[6];
            { float4 f = *(const float4*)(Kr + d4); kc[0]=f.x; kc[1]=f.y; kc[2]=f.z; kc[3]=f.w;
              float2 g2 = *(const float2*)(Kr + dlo); kc[4]=g2.x; kc[5]=g2.y; }
            { float4 f = *(const float4*)(Ar + d4); ac[0]=f.x; ac[1]=f.y; ac[2]=f.z; ac[3]=f.w;
              float2 g2 = *(const float2*)(Ar + dlo); ac[4]=g2.x; ac[5]=g2.y; }
            { float4 f = *(const float4*)(Qr + d4); qc[0]=f.x; qc[1]=f.y; qc[2]=f.z; qc[3]=f.w;
              float2 g2 = *(const float2*)(Qr + dlo); qc[4]=g2.x; qc[5]=g2.y; }
            const float vc  = Vt[buf][cb][tt];
            const float bS  = St[buf][0][tt];
            const float d2S = St[buf][1][tt];
            const float r2S = St[buf][2][tt];

            // r1 = red32( sum_j k a a_prev * sd )
            float p0 = 0.f, p1 = 0.f;
#pragma unroll
            for (int j = 0; j < 6; j++) {
                float kaa = kc[j] * ac[j] * apv[j];
                if (j & 1) p1 = fmaf(kaa, sd[j], p1); else p0 = fmaf(kaa, sd[j], p0);
            }
            float r1 = red32(p0 + p1);

            float ut = bS * vc - bS * r1 - u2 * r2S - u1 * d2S;

            // sd -> S~_{t-1}
#pragma unroll
            for (int j = 0; j < 6; j++)
                sd[j] = apv[j] * fmaf(u2, kp2[j], sd[j]);

            // o_{t-1}
            float o0 = 0.f, o1 = 0.f;
#pragma unroll
            for (int j = 0; j < 6; j++) {
                float tmp = fmaf(u1, kp1[j], sd[j]);
                if (j & 1) o1 = fmaf(qpv[j], tmp, o1); else o0 = fmaf(qpv[j], tmp, o0);
            }
            float ov = red32(o0 + o1);
            if (isnan(ov)) ov = 0.f;
            else if (isinf(ov)) ov = ov > 0.f ? 1e4f : -1e4f;
            if (l == 0 && t > 0) op[(size_t)(t - 1) * (HH * DV)] = ov;

            // rotate registers
#pragma unroll
            for (int j = 0; j < 6; j++) {
                kp2[j] = kp1[j]; kp1[j] = kc[j]; qpv[j] = qc[j]; apv[j] = ac[j];
            }
            u2 = u1; u1 = ut;
        }
        __syncthreads();   // all waves done reading buf
        if (n + 2 < TT / TB) stage(buf, n + 2);
    }

    // epilogue: o_{TT-1}
    {
#pragma unroll
        for (int j = 0; j < 6; j++)
            sd[j] = apv[j] * fmaf(u2, kp2[j], sd[j]);
        float o0 = 0.f, o1 = 0.f;
#pragma unroll
        for (int j = 0; j < 6; j++) {
            float tmp = fmaf(u1, kp1[j], sd[j]);
            if (j & 1) o1 = fmaf(qpv[j], tmp, o1); else o0 = fmaf(qpv[j], tmp, o0);
        }
        float ov = red32(o0 + o1);
        if (isnan(ov)) ov = 0.f;
        else if (isinf(ov)) ov = ov > 0.f ? 1e4f : -1e4f;
        if (l == 0) op[(size_t)(TT - 1) * (HH * DV)] = ov;
    }
}

// ---------------------------------------------------------------------------
extern "C" void kernel_launch(void* const* d_in, const int* in_sizes, int n_in,
                              void* d_out, int out_size, void* d_ws, size_t ws_size,
                              hipStream_t stream)
{
    const float* x         = (const float*)d_in[0];
    // d_in[1] = cos, d_in[2] = sin : unused by the reference
    const float* wq_a      = (const float*)d_in[3];
    const float* q_norm_w  = (const float*)d_in[4];
    const float* wq_b      = (const float*)d_in[5];
    const float* wkv_a     = (const float*)d_in[6];
    const float* kv_norm_w = (const float*)d_in[7];
    const float* wkv_b     = (const float*)d_in[8];
    const float* wg_w      = (const float*)d_in[9];
    const float* wg_b      = (const float*)d_in[10];
    const float* wb        = (const float*)d_in[11];
    const float* wo        = (const float*)d_in[12];
    float* out = (float*)d_out;

    float* ws = (float*)d_ws;
    float* xq     = ws;                        // T x 768 (rms in-place)
    float* kv_all = xq     + TT * QLR;         // T x 576
    float* kvn    = kv_all + TT * (KVLR + DROPE); // T x 512
    float* agraw  = kvn    + TT * KVLR;        // T x 1536 (dead after sigmoid)
    float* ob     = agraw;                     // alias: T x 1024 (scan output)
    float* qnraw  = agraw  + TT * HDK;         // T x 1536 (dead after prep_qk)
    float* v_h    = qnraw;                     // alias: 8 x 128 x 1024
    float* kvb    = qnraw  + TT * HDK;         // T x 2048
    float* a_h    = kvb    + TT * HKV;         // 8 x 1024 x 192
    float* q_h    = a_h    + TT * HDK;         // 8 x 1024 x 192
    float* k_h    = q_h    + TT * HDK;         // 8 x 1024 x 192
    float* betab  = k_h    + TT * HDK;         // T x 8
    float* beta_h = betab  + TT * HH;          // 8 x 1024
    float* d2_h   = beta_h + TT * HH;          // 8 x 1024
    float* r2_h   = d2_h   + TT * HH;          // 8 x 1024

    dim3 blk(256);

    // x projections
    gemm64<<<dim3(QLR / 64, TT / 64), blk, 0, stream>>>(x, wq_a, xq, TT, QLR, DIM);
    gemm64<<<dim3((KVLR + DROPE) / 64, TT / 64), blk, 0, stream>>>(x, wkv_a, kv_all, TT, KVLR + DROPE, DIM);
    gemm64<<<dim3(HDK / 64, TT / 64), blk, 0, stream>>>(x, wg_w, agraw, TT, HDK, DIM);

    // norms
    rmsnorm_rows<<<TT, blk, 0, stream>>>(xq, QLR, q_norm_w, xq, QLR, QLR, 1.f / QLR);
    rmsnorm_rows<<<TT, blk, 0, stream>>>(kv_all, KVLR + DROPE, kv_norm_w, kvn, KVLR, KVLR, 1.f / KVLR);

    // low-rank expansions
    gemm64<<<dim3(HDK / 64, TT / 64), blk, 0, stream>>>(xq, wq_b, qnraw, TT, HDK, QLR);
    gemm64<<<dim3(HKV / 64, TT / 64), blk, 0, stream>>>(kvn, wkv_b, kvb, TT, HKV, KVLR);

    // gates (head-major relayout)
    sigmoid_relayout<<<(TT * HDK + 255) / 256, blk, 0, stream>>>(agraw, wg_b, a_h);
    beta_kernel<<<TT * HH / 4, blk, 0, stream>>>(x, wb, betab, beta_h);

    // l2norm q, build+l2norm k (head-major)
    prep_qk<<<TT * HH / 4, blk, 0, stream>>>(qnraw, kvb, kv_all, q_h, k_h);

    // v transpose (after prep_qk: v_h aliases qnraw)
    vtrans<<<64, blk, 0, stream>>>(kvb, v_h);

    // input-only scalar precompute
    prep_scalars<<<TT * HH / 4, blk, 0, stream>>>(k_h, a_h, betab, d2_h, r2_h);

    // LDS-staged gated delta-rule scan (ob aliases agraw)
    kda_scan4<<<128, blk, 0, stream>>>(q_h, k_h, a_h, v_h, beta_h, d2_h, r2_h, ob);

    // output projection
    gemm64<<<dim3(DIM / 64, TT / 64), blk, 0, stream>>>(ob, wo, out, TT, DIM, DIM);
}